// Round 1
// baseline (112.434 us; speedup 1.0000x reference)
//
#include <hip/hip_runtime.h>
#include <math.h>

#define B_TOK 8192
#define NB 4
#define CH 2048
#define TPB 256
#define SINK_ITERS 20
#define EPS 1e-5f

// Kernel 1: tiny 4x4 Sinkhorn + sigmoids -> 24 floats in workspace.
// ws[0..15] = H (row-major), ws[16..19] = pre, ws[20..23] = post
__global__ void mhc_sinkhorn(const float* __restrict__ H_pre,
                             const float* __restrict__ H_post,
                             const float* __restrict__ H_res,
                             float* __restrict__ ws)
{
    if (threadIdx.x == 0) {
        float M[NB][NB];
        #pragma unroll
        for (int i = 0; i < NB; ++i)
            #pragma unroll
            for (int j = 0; j < NB; ++j)
                M[i][j] = expf(H_res[i * NB + j]);

        for (int it = 0; it < SINK_ITERS; ++it) {
            // row normalize
            #pragma unroll
            for (int i = 0; i < NB; ++i) {
                float s = M[i][0] + M[i][1] + M[i][2] + M[i][3] + EPS;
                float r = 1.0f / s;
                #pragma unroll
                for (int j = 0; j < NB; ++j) M[i][j] *= r;
            }
            // col normalize
            #pragma unroll
            for (int j = 0; j < NB; ++j) {
                float s = M[0][j] + M[1][j] + M[2][j] + M[3][j] + EPS;
                float r = 1.0f / s;
                #pragma unroll
                for (int i = 0; i < NB; ++i) M[i][j] *= r;
            }
        }
        #pragma unroll
        for (int i = 0; i < NB; ++i)
            #pragma unroll
            for (int j = 0; j < NB; ++j)
                ws[i * NB + j] = M[i][j];
        #pragma unroll
        for (int n = 0; n < NB; ++n) {
            ws[16 + n] = 1.0f / (1.0f + expf(-H_pre[n]));
            ws[20 + n] = 1.0f / (1.0f + expf(-H_post[n]));
        }
    }
}

// Kernel 2: fused RMSNorm + aggregate + mix + redistribute.
// One block per token b. Each thread owns 8 channels across all 4 branches,
// held in registers; x is read exactly once, y written exactly once.
__global__ __launch_bounds__(TPB) void mhc_main(const float* __restrict__ x,
                                                const float* __restrict__ w,
                                                const float* __restrict__ ws,
                                                float* __restrict__ y)
{
    const int b = blockIdx.x;
    const int t = threadIdx.x;
    const int wave = t >> 6;
    const int lane = t & 63;

    // Broadcast the 24 mixing scalars (uniform -> scalar loads)
    float H[NB][NB], pre[NB], post[NB];
    #pragma unroll
    for (int i = 0; i < NB; ++i)
        #pragma unroll
        for (int j = 0; j < NB; ++j)
            H[i][j] = ws[i * NB + j];
    #pragma unroll
    for (int n = 0; n < NB; ++n) {
        pre[n]  = ws[16 + n];
        post[n] = ws[20 + n];
    }

    // Load x[b, n, :]: per branch n, two coalesced float4 chunks
    // (thread t -> float4 index t and 256+t within the 512-float4 row).
    const float4* xb = (const float4*)(x + (size_t)b * NB * CH);
    float4 xv[NB][2];
    float ss[NB];
    #pragma unroll
    for (int n = 0; n < NB; ++n) {
        xv[n][0] = xb[n * (CH / 4) + t];
        xv[n][1] = xb[n * (CH / 4) + (TPB) + t];
        float4 a = xv[n][0], c = xv[n][1];
        ss[n] = a.x * a.x + a.y * a.y + a.z * a.z + a.w * a.w +
                c.x * c.x + c.y * c.y + c.z * c.z + c.w * c.w;
    }

    // Wave reduce (64 lanes), then combine 4 waves via LDS.
    #pragma unroll
    for (int m = 1; m < 64; m <<= 1) {
        #pragma unroll
        for (int n = 0; n < NB; ++n)
            ss[n] += __shfl_xor(ss[n], m);
    }
    __shared__ float red[4][NB];
    if (lane == 0) {
        #pragma unroll
        for (int n = 0; n < NB; ++n) red[wave][n] = ss[n];
    }
    __syncthreads();

    float inv[NB];
    #pragma unroll
    for (int n = 0; n < NB; ++n) {
        float tot = red[0][n] + red[1][n] + red[2][n] + red[3][n];
        inv[n] = rsqrtf(tot * (1.0f / CH) + EPS);
    }

    // rmsnorm weight for this thread's 8 channels
    const float4* wv4 = (const float4*)w;
    float4 w0 = wv4[t], w1 = wv4[TPB + t];
    float wv[8] = { w0.x, w0.y, w0.z, w0.w, w1.x, w1.y, w1.z, w1.w };

    // Unpack x into [branch][8] register array (all-static indexing)
    float xr[NB][8];
    #pragma unroll
    for (int n = 0; n < NB; ++n) {
        xr[n][0] = xv[n][0].x; xr[n][1] = xv[n][0].y;
        xr[n][2] = xv[n][0].z; xr[n][3] = xv[n][0].w;
        xr[n][4] = xv[n][1].x; xr[n][5] = xv[n][1].y;
        xr[n][6] = xv[n][1].z; xr[n][7] = xv[n][1].w;
    }

    // x_agg[c] = sum_n pre[n] * x_norm[n][c]
    float agg[8];
    #pragma unroll
    for (int k = 0; k < 8; ++k) {
        float a = 0.0f;
        #pragma unroll
        for (int n = 0; n < NB; ++n)
            a += pre[n] * (xr[n][k] * inv[n] * wv[k]);
        agg[k] = a;
    }

    // y[b][m][c] = sum_n H[m][n]*x[n][c] + post[m]*agg[c]
    float4* yb = (float4*)(y + (size_t)b * NB * CH);
    #pragma unroll
    for (int m = 0; m < NB; ++m) {
        float out[8];
        #pragma unroll
        for (int k = 0; k < 8; ++k) {
            float v = post[m] * agg[k];
            #pragma unroll
            for (int n = 0; n < NB; ++n)
                v += H[m][n] * xr[n][k];
            out[k] = v;
        }
        float4 o0 = { out[0], out[1], out[2], out[3] };
        float4 o1 = { out[4], out[5], out[6], out[7] };
        yb[m * (CH / 4) + t]       = o0;
        yb[m * (CH / 4) + TPB + t] = o1;
    }
}

extern "C" void kernel_launch(void* const* d_in, const int* in_sizes, int n_in,
                              void* d_out, int out_size, void* d_ws, size_t ws_size,
                              hipStream_t stream) {
    const float* x      = (const float*)d_in[0];   // [B, N, C]
    const float* wgt    = (const float*)d_in[1];   // [C]
    const float* h_pre  = (const float*)d_in[2];   // [N]
    const float* h_post = (const float*)d_in[3];   // [N]
    const float* h_res  = (const float*)d_in[4];   // [N, N]
    float* y  = (float*)d_out;                     // [B, N, C]
    float* ws = (float*)d_ws;                      // >= 24 floats

    mhc_sinkhorn<<<1, 64, 0, stream>>>(h_pre, h_post, h_res, ws);
    mhc_main<<<B_TOK, TPB, 0, stream>>>(x, wgt, ws, y);
}